// Round 10
// baseline (85.974 us; speedup 1.0000x reference)
//
#include <hip/hip_runtime.h>
#include <limits.h>

#define NB      2
#define N_Q     20000
#define NBQ     (NB * N_Q)          // 40000
#define M_V     6890
#define N_F     13776
#define NBF     (NB * N_F)          // 27552
#define RAD2    0.01f               // 0.1^2
#define THRESH  0.001f
#define EPSN    1e-7f
#define SCALE   (1.0f / (float)(NB * N_Q))

// grid: 12^3, cell h=0.2 = 2*radius, span [-1.2, 1.2] clamped.
// With h = 2r, the radius window spans at most 2 cells per axis (home cell
// plus the neighbor on the query's side of the cell). Clamp is monotone and
// applied identically to faces and queries; collapsed neighbors dedup via
// the [lo,hi] interval.
#define GDIM    12
#define NCELLS  (GDIM * GDIM * GDIM)        // 1728
#define T_CELLS (NB * NCELLS)               // 3456
#define H_INV   5.0f
#define ORG     (-1.2f)

#define CAP     128                 // faces per cell bucket (peak ~36 expected)

#define QPB     8                   // queries per block (1 per 32-lane half-wave)
#define QBLOCKS (NBQ / QPB)         // 5000 exactly

__device__ __forceinline__ int cell_coord(float x) {
    int g = (int)floorf((x - ORG) * H_INV);
    return min(max(g, 0), GDIM - 1);
}

// [lo,hi] cell window (1 or 2 cells) for a radius-r interval, h = 2r
__device__ __forceinline__ void axis_window(float v, int& lo, int& hi) {
    float s  = (v - ORG) * H_INV;
    float fl = floorf(s);
    int g_u  = (int)fl;
    int g    = min(max(g_u, 0), GDIM - 1);
    int sy   = ((s - fl) >= 0.5f) ? 1 : -1;
    int g2   = min(max(g_u + sy, 0), GDIM - 1);
    lo = min(g, g2);
    hi = max(g, g2);
}

__device__ __forceinline__ int half_min_i(int v) {
    #pragma unroll
    for (int m = 16; m; m >>= 1) v = min(v, __shfl_xor(v, m));
    return v;
}

// ---------------- Kernel 1: per-face precompute + direct bucket scatter ----
__global__ __launch_bounds__(256) void face_kernel(
    const float* __restrict__ h_state,   // [NB][M_V][9]
    const int*   __restrict__ h_faces,   // [NB][N_F][3]
    float4* __restrict__ posn,           // [2*NBF]: {pos, nrm} interleaved
    float4* __restrict__ buckets,        // [T_CELLS*CAP]: prev pos + id
    int* __restrict__ cellCnt,           // [T_CELLS]
    float* __restrict__ out)
{
    int t = blockIdx.x * 256 + threadIdx.x;
    if (t == 0) out[0] = 0.0f;           // zero accumulator before query kernel
    if (t >= NBF) return;
    int b = t / N_F;
    const int* fc = h_faces + (size_t)t * 3;
    int i0 = fc[0], i1 = fc[1], i2 = fc[2];
    const float* hs = h_state + (size_t)b * M_V * 9;

    // per vertex: 9-float row; cols 0..2 = t1 pos, cols 6..8 = t0 pos.
    // two dwordx4 loads (4B alignment is sufficient).
    const float* v0 = hs + (size_t)i0 * 9;
    const float* v1 = hs + (size_t)i1 * 9;
    const float* v2 = hs + (size_t)i2 * 9;
    float4 a0 = *(const float4*)(v0);       // cols 0,1,2,3
    float4 a1 = *(const float4*)(v0 + 5);   // cols 5,6,7,8
    float4 b0 = *(const float4*)(v1);
    float4 b1 = *(const float4*)(v1 + 5);
    float4 c0 = *(const float4*)(v2);
    float4 c1 = *(const float4*)(v2 + 5);

    float px = (a0.x + b0.x + c0.x) / 3.0f;
    float py = (a0.y + b0.y + c0.y) / 3.0f;
    float pz = (a0.z + b0.z + c0.z) / 3.0f;

    float e1x = b0.x - a0.x, e1y = b0.y - a0.y, e1z = b0.z - a0.z;
    float e2x = c0.x - a0.x, e2y = c0.y - a0.y, e2z = c0.z - a0.z;
    float nx = e1y * e2z - e1z * e2y;
    float ny = e1z * e2x - e1x * e2z;
    float nz = e1x * e2y - e1y * e2x;
    float nrm = sqrtf(nx * nx + ny * ny + nz * nz);
    float den = fmaxf(nrm, EPSN);
    nx /= den; ny /= den; nz /= den;

    float qx = (a1.y + b1.y + c1.y) / 3.0f;   // col 6
    float qy = (a1.z + b1.z + c1.z) / 3.0f;   // col 7
    float qz = (a1.w + b1.w + c1.w) / 3.0f;   // col 8

    posn[2 * t]     = make_float4(px, py, pz, 0.0f);
    posn[2 * t + 1] = make_float4(nx, ny, nz, 0.0f);

    int gx = cell_coord(qx), gy = cell_coord(qy), gz = cell_coord(qz);
    int cid = b * NCELLS + (gz * GDIM + gy) * GDIM + gx;
    int slot = atomicAdd(&cellCnt[cid], 1);
    if (slot < CAP)   // statistically unreachable guard (peak ~36 of 128)
        buckets[(size_t)cid * CAP + slot] = make_float4(qx, qy, qz, __int_as_float(t));
}

// ---------------- Kernel 2: half-wave (32 lanes) per query -----------------
#define CSW(a, b) { int _mn = min(a, b); int _mx = max(a, b); a = _mn; b = _mx; }

__global__ __launch_bounds__(256) void query_kernel(
    const float*  __restrict__ state,    // x_t0 queries
    const float*  __restrict__ pred,     // x_t1 for loss
    const float4* __restrict__ buckets,
    const float4* __restrict__ posn,
    const int* __restrict__ cellCnt,
    float* __restrict__ out)
{
    __shared__ int   smCnt[NCELLS];      // this batch's cell counts (6.9 KB)
    __shared__ float ws[QPB];

    int tid  = threadIdx.x;
    int l32  = tid & 31;
    int hw   = tid >> 5;                 // half-wave id 0..7
    int q    = blockIdx.x * QPB + hw;    // always < NBQ (exact grid)
    int b    = (q >= N_Q) ? 1 : 0;       // uniform per block (20000 % 8 == 0)

    // cooperative stage of this batch's 1728 cell counts into LDS
    {
        const int4* src = (const int4*)(cellCnt + b * NCELLS);
        int4* dst = (int4*)smCnt;
        #pragma unroll
        for (int i = tid; i < NCELLS / 4; i += 256)
            dst[i] = src[i];
    }

    const float* st = state + (size_t)q * 3;
    float qx = st[0], qy = st[1], qz = st[2];
    const float* pr = pred + (size_t)q * 3;
    float x = pr[0], y = pr[1], z = pr[2];

    // cnt==0 fallback face (face 0 of batch) -- static address
    float4 P0 = posn[2 * (b * N_F)];
    float4 N0 = posn[2 * (b * N_F) + 1];

    int xlo, xhi, ylo, yhi, zlo, zhi;
    axis_window(qx, xlo, xhi);
    axis_window(qy, ylo, yhi);
    axis_window(qz, zlo, zhi);

    __syncthreads();                     // smCnt ready

    // 8-cell (2x2x2) window: register cum/off chain, counts from LDS
    int cum1, cum2, cum3, cum4, cum5, cum6, cum7, cum8;
    int off0, off1, off2, off3, off4, off5, off6, off7;
    {
        int bN = b * NCELLS;
        #define CELL(CI, CUMP, CUMN, OFFR)                                  \
        {                                                                   \
            int gz = zlo + ((CI) >> 2);                                     \
            int gy = ylo + (((CI) >> 1) & 1);                               \
            int gx = xlo + ((CI) & 1);                                      \
            int len = 0, base = 0;                                          \
            if (gz <= zhi && gy <= yhi && gx <= xhi) {                      \
                int c = (gz * GDIM + gy) * GDIM + gx;                       \
                len = smCnt[c];                                             \
                base = (bN + c) * CAP;                                      \
            }                                                               \
            OFFR = base - CUMP;                                             \
            CUMN = CUMP + len;                                              \
        }
        int c0 = 0;
        CELL(0, c0,   cum1, off0)
        CELL(1, cum1, cum2, off1)
        CELL(2, cum2, cum3, off2)
        CELL(3, cum3, cum4, off3)
        CELL(4, cum4, cum5, off4)
        CELL(5, cum5, cum6, off5)
        CELL(6, cum6, cum7, off6)
        CELL(7, cum7, cum8, off7)
        #undef CELL
    }
    int C = cum8;

    // 32 lanes split this query's candidate union
    int s0 = INT_MAX, s1 = INT_MAX, s2 = INT_MAX, s3 = INT_MAX;
    int s4 = INT_MAX, s5 = INT_MAX, s6 = INT_MAX, s7 = INT_MAX;
    int cnt = 0;
    float fsum = 0.0f;
    int   lmin = INT_MAX;
    float fmin = 0.0f;

    int iters = (C + 31) >> 5;
    for (int it = 0; it < iters; ++it) {
        int k = (it << 5) + l32;
        int addr = off0 + k;
        addr = (k >= cum1) ? off1 + k : addr;
        addr = (k >= cum2) ? off2 + k : addr;
        addr = (k >= cum3) ? off3 + k : addr;
        addr = (k >= cum4) ? off4 + k : addr;
        addr = (k >= cum5) ? off5 + k : addr;
        addr = (k >= cum6) ? off6 + k : addr;
        addr = (k >= cum7) ? off7 + k : addr;
        if (k < C) {
            float4 p = buckets[addr];
            float ddx = p.x - qx, ddy = p.y - qy, ddz = p.z - qz;
            float d2 = ddx * ddx + ddy * ddy + ddz * ddz;
            if (d2 < RAD2) {
                ++cnt;
                int tf = __float_as_int(p.w);
                float4 P  = posn[2 * tf];
                float4 Nn = posn[2 * tf + 1];
                float d = (x - P.x) * Nn.x + (y - P.y) * Nn.y + (z - P.z) * Nn.z;
                float ip = fmaxf(THRESH - d, 0.0f);
                float f = ip * ip * ip;
                fsum += f;
                if (tf < lmin) { lmin = tf; fmin = f; }
                if (tf < s7) {
                    s7 = tf;
                    CSW(s6, s7); CSW(s5, s6); CSW(s4, s5); CSW(s3, s4);
                    CSW(s2, s3); CSW(s1, s2); CSW(s0, s1);
                }
            }
        }
    }

    // fused 5-step butterfly within the half-wave:
    // (sum cnt, sum f, argmin pair) simultaneously
    int   c_ = cnt;
    float fs = fsum;
    int   lm = lmin;
    float fm = fmin;
    #pragma unroll
    for (int m = 16; m; m >>= 1) {
        int   oc = __shfl_xor(c_, m);
        float os = __shfl_xor(fs, m);
        int   ol = __shfl_xor(lm, m);
        float of = __shfl_xor(fm, m);
        c_ += oc;
        fs += os;
        if (ol < lm) { lm = ol; fm = of; }
    }
    int cnt_tot = c_;            // uniform within half-wave

    float lsum;
    if (cnt_tot == 0) {
        float d0 = (x - P0.x) * N0.x + (y - P0.y) * N0.y + (z - P0.z) * N0.z;
        float ip0 = fmaxf(THRESH - d0, 0.0f);
        lsum = 8.0f * (ip0 * ip0 * ip0);
    } else if (cnt_tot <= 8) {
        // selected set == all hits; pad (8-cnt) copies of the min-id hit
        lsum = fs + (float)(8 - cnt_tot) * fm;
    } else {
        // slow path: extract the 8 smallest ids (unique across lanes)
        int t0, t1, t2, t3, t4, t5, t6, t7;
#define EXTRACT(TK)                                                      \
        {                                                                \
            int m = half_min_i(s0);                                      \
            TK = m;                                                      \
            bool p = (s0 == m);                                          \
            s0 = p ? s1 : s0; s1 = p ? s2 : s1; s2 = p ? s3 : s2;        \
            s3 = p ? s4 : s3; s4 = p ? s5 : s4; s5 = p ? s6 : s5;        \
            s6 = p ? s7 : s6; s7 = p ? INT_MAX : s7;                     \
        }
        EXTRACT(t0) EXTRACT(t1) EXTRACT(t2) EXTRACT(t3)
        EXTRACT(t4) EXTRACT(t5) EXTRACT(t6) EXTRACT(t7)
#undef EXTRACT
        int v = t0;
        v = (l32 == 1) ? t1 : v;
        v = (l32 == 2) ? t2 : v;
        v = (l32 == 3) ? t3 : v;
        v = (l32 == 4) ? t4 : v;
        v = (l32 == 5) ? t5 : v;
        v = (l32 == 6) ? t6 : v;
        v = (l32 == 7) ? t7 : v;
        float4 P  = posn[2 * v];
        float4 Nn = posn[2 * v + 1];
        float d = (x - P.x) * Nn.x + (y - P.y) * Nn.y + (z - P.z) * Nn.z;
        float ip = fmaxf(THRESH - d, 0.0f);
        float c = ip * ip * ip;
        c = (l32 < 8) ? c : 0.0f;
        #pragma unroll
        for (int m = 16; m; m >>= 1) c += __shfl_xor(c, m);
        lsum = c;
    }

    if (l32 == 0) ws[hw] = lsum;
    __syncthreads();
    if (tid == 0) {
        float s = 0.0f;
        #pragma unroll
        for (int k = 0; k < QPB; ++k) s += ws[k];
        atomicAdd(out, s * SCALE);   // one pipelined L2 atomic per block
    }
}

extern "C" void kernel_launch(void* const* d_in, const int* in_sizes, int n_in,
                              void* d_out, int out_size, void* d_ws, size_t ws_size,
                              hipStream_t stream) {
    const float* pred    = (const float*)d_in[0];
    const float* state   = (const float*)d_in[1];
    const float* h_state = (const float*)d_in[2];
    const int*   h_faces = (const int*)d_in[3];
    float* out = (float*)d_out;

    // workspace layout (~8.0 MB)
    float4* posn    = (float4*)d_ws;                     // 2*NBF
    float4* buckets = posn + 2 * NBF;                    // T_CELLS*CAP
    int* cellCnt    = (int*)(buckets + (size_t)T_CELLS * CAP); // T_CELLS

    hipMemsetAsync(cellCnt, 0, (size_t)T_CELLS * sizeof(int), stream);

    face_kernel<<<dim3((NBF + 255) / 256), 256, 0, stream>>>(
        h_state, h_faces, posn, buckets, cellCnt, out);

    query_kernel<<<dim3(QBLOCKS), 256, 0, stream>>>(
        state, pred, buckets, posn, cellCnt, out);
}

// Round 11
// 39.805 us; speedup vs baseline: 2.1599x; 2.1599x over previous
//
#include <hip/hip_runtime.h>
#include <limits.h>

#define NB      2
#define N_Q     20000
#define NBQ     (NB * N_Q)          // 40000
#define M_V     6890
#define N_F     13776
#define NBF     (NB * N_F)          // 27552
#define RAD2    0.01f               // 0.1^2
#define THRESH  0.001f
#define EPSN    1e-7f
#define SCALE   (1.0f / (float)(NB * N_Q))

// grid: 12^3, cell h=0.2 = 2*radius, span [-1.2, 1.2] clamped.
// With h = 2r, the radius window spans at most 2 cells per axis (home cell
// plus the neighbor on the query's side of the cell). Clamp is monotone and
// applied identically to faces and queries; collapsed neighbors dedup via
// the [lo,hi] interval.
#define GDIM    12
#define NCELLS  (GDIM * GDIM * GDIM)        // 1728
#define T_CELLS (NB * NCELLS)               // 3456
#define H_INV   5.0f
#define ORG     (-1.2f)

#define CAP     128                 // faces per cell bucket (peak ~36 expected)

#define QPB     8                   // queries per block (1 per 32-lane half-wave)
#define QBLOCKS (NBQ / QPB)         // 5000 exactly
#define B_SPLIT (N_Q / QPB)         // 2500: blocks [0,2500) are batch 0

__device__ __forceinline__ int cell_coord(float x) {
    int g = (int)floorf((x - ORG) * H_INV);
    return min(max(g, 0), GDIM - 1);
}

// [lo,hi] cell window (1 or 2 cells) for a radius-r interval, h = 2r
__device__ __forceinline__ void axis_window(float v, int& lo, int& hi) {
    float s  = (v - ORG) * H_INV;
    float fl = floorf(s);
    int g_u  = (int)fl;
    int g    = min(max(g_u, 0), GDIM - 1);
    int sy   = ((s - fl) >= 0.5f) ? 1 : -1;
    int g2   = min(max(g_u + sy, 0), GDIM - 1);
    lo = min(g, g2);
    hi = max(g, g2);
}

__device__ __forceinline__ float wave_add_f(float v) {
    #pragma unroll
    for (int m = 32; m; m >>= 1) v += __shfl_xor(v, m);
    return v;
}
__device__ __forceinline__ int half_min_i(int v) {
    #pragma unroll
    for (int m = 16; m; m >>= 1) v = min(v, __shfl_xor(v, m));
    return v;
}

// ---------------- Kernel 1: per-face precompute + direct bucket scatter ----
__global__ __launch_bounds__(256) void face_kernel(
    const float* __restrict__ h_state,   // [NB][M_V][9]
    const int*   __restrict__ h_faces,   // [NB][N_F][3]
    float4* __restrict__ posn,           // [2*NBF]: {pos, nrm} interleaved
    float4* __restrict__ buckets,        // [T_CELLS*CAP]: prev pos + id
    int* __restrict__ cellCnt)           // [T_CELLS]
{
    int t = blockIdx.x * 256 + threadIdx.x;
    if (t >= NBF) return;
    int b = t / N_F;
    const int* fc = h_faces + (size_t)t * 3;
    int i0 = fc[0], i1 = fc[1], i2 = fc[2];
    const float* hs = h_state + (size_t)b * M_V * 9;

    // per vertex: 9-float row; cols 0..2 = t1 pos, cols 6..8 = t0 pos.
    // two dwordx4 loads per vertex (4B alignment is sufficient).
    const float* v0 = hs + (size_t)i0 * 9;
    const float* v1 = hs + (size_t)i1 * 9;
    const float* v2 = hs + (size_t)i2 * 9;
    float4 a0 = *(const float4*)(v0);       // cols 0,1,2,3
    float4 a1 = *(const float4*)(v0 + 5);   // cols 5,6,7,8
    float4 b0 = *(const float4*)(v1);
    float4 b1 = *(const float4*)(v1 + 5);
    float4 c0 = *(const float4*)(v2);
    float4 c1 = *(const float4*)(v2 + 5);

    float px = (a0.x + b0.x + c0.x) / 3.0f;
    float py = (a0.y + b0.y + c0.y) / 3.0f;
    float pz = (a0.z + b0.z + c0.z) / 3.0f;

    float e1x = b0.x - a0.x, e1y = b0.y - a0.y, e1z = b0.z - a0.z;
    float e2x = c0.x - a0.x, e2y = c0.y - a0.y, e2z = c0.z - a0.z;
    float nx = e1y * e2z - e1z * e2y;
    float ny = e1z * e2x - e1x * e2z;
    float nz = e1x * e2y - e1y * e2x;
    float nrm = sqrtf(nx * nx + ny * ny + nz * nz);
    float den = fmaxf(nrm, EPSN);
    nx /= den; ny /= den; nz /= den;

    float qx = (a1.y + b1.y + c1.y) / 3.0f;   // col 6
    float qy = (a1.z + b1.z + c1.z) / 3.0f;   // col 7
    float qz = (a1.w + b1.w + c1.w) / 3.0f;   // col 8

    posn[2 * t]     = make_float4(px, py, pz, 0.0f);
    posn[2 * t + 1] = make_float4(nx, ny, nz, 0.0f);

    int gx = cell_coord(qx), gy = cell_coord(qy), gz = cell_coord(qz);
    int cid = b * NCELLS + (gz * GDIM + gy) * GDIM + gx;
    int slot = atomicAdd(&cellCnt[cid], 1);
    if (slot < CAP)   // statistically unreachable guard (peak ~36 of 128)
        buckets[(size_t)cid * CAP + slot] = make_float4(qx, qy, qz, __int_as_float(t));
}

// ---------------- Kernel 2: half-wave (32 lanes) per query -----------------
#define CSW(a, b) { int _mn = min(a, b); int _mx = max(a, b); a = _mn; b = _mx; }

__global__ __launch_bounds__(256) void query_kernel(
    const float*  __restrict__ state,    // x_t0 queries
    const float*  __restrict__ pred,     // x_t1 for loss
    const float4* __restrict__ buckets,
    const float4* __restrict__ posn,
    const int* __restrict__ cellCnt,
    float* __restrict__ partials)
{
    __shared__ float ws[QPB];

    int tid  = threadIdx.x;
    int l32  = tid & 31;
    int hw   = tid >> 5;                 // half-wave id 0..7
    int q    = blockIdx.x * QPB + hw;    // always < NBQ (exact grid)
    int b    = (blockIdx.x >= B_SPLIT) ? 1 : 0;   // uniform per block

    const float* st = state + (size_t)q * 3;
    float qx = st[0], qy = st[1], qz = st[2];
    const float* pr = pred + (size_t)q * 3;
    float x = pr[0], y = pr[1], z = pr[2];

    // cnt==0 fallback face (face 0 of batch) -- static address
    float4 P0 = posn[2 * (b * N_F)];
    float4 N0 = posn[2 * (b * N_F) + 1];

    int xlo, xhi, ylo, yhi, zlo, zhi;
    axis_window(qx, xlo, xhi);
    axis_window(qy, ylo, yhi);
    axis_window(qz, zlo, zhi);

    // 8-cell (2x2x2) window: register cum/off chain, fully static
    int cum1, cum2, cum3, cum4, cum5, cum6, cum7, cum8;
    int off0, off1, off2, off3, off4, off5, off6, off7;
    {
        int bN = b * NCELLS;
        #define CELL(CI, CUMP, CUMN, OFFR)                                  \
        {                                                                   \
            int gz = zlo + ((CI) >> 2);                                     \
            int gy = ylo + (((CI) >> 1) & 1);                               \
            int gx = xlo + ((CI) & 1);                                      \
            int len = 0, base = 0;                                          \
            if (gz <= zhi && gy <= yhi && gx <= xhi) {                      \
                int c = bN + (gz * GDIM + gy) * GDIM + gx;                  \
                len = cellCnt[c];                                           \
                base = c * CAP;                                             \
            }                                                               \
            OFFR = base - CUMP;                                             \
            CUMN = CUMP + len;                                              \
        }
        int c0 = 0;
        CELL(0, c0,   cum1, off0)
        CELL(1, cum1, cum2, off1)
        CELL(2, cum2, cum3, off2)
        CELL(3, cum3, cum4, off3)
        CELL(4, cum4, cum5, off4)
        CELL(5, cum5, cum6, off5)
        CELL(6, cum6, cum7, off6)
        CELL(7, cum7, cum8, off7)
        #undef CELL
    }
    int C = cum8;

    // 32 lanes split this query's candidate union
    int s0 = INT_MAX, s1 = INT_MAX, s2 = INT_MAX, s3 = INT_MAX;
    int s4 = INT_MAX, s5 = INT_MAX, s6 = INT_MAX, s7 = INT_MAX;
    int cnt = 0;
    float fsum = 0.0f;
    int   lmin = INT_MAX;
    float fmin = 0.0f;

    int iters = (C + 31) >> 5;
    for (int it = 0; it < iters; ++it) {
        int k = (it << 5) + l32;
        int addr = off0 + k;
        addr = (k >= cum1) ? off1 + k : addr;
        addr = (k >= cum2) ? off2 + k : addr;
        addr = (k >= cum3) ? off3 + k : addr;
        addr = (k >= cum4) ? off4 + k : addr;
        addr = (k >= cum5) ? off5 + k : addr;
        addr = (k >= cum6) ? off6 + k : addr;
        addr = (k >= cum7) ? off7 + k : addr;
        if (k < C) {
            float4 p = buckets[addr];
            float ddx = p.x - qx, ddy = p.y - qy, ddz = p.z - qz;
            float d2 = ddx * ddx + ddy * ddy + ddz * ddz;
            if (d2 < RAD2) {
                ++cnt;
                int tf = __float_as_int(p.w);
                float4 P  = posn[2 * tf];
                float4 Nn = posn[2 * tf + 1];
                float d = (x - P.x) * Nn.x + (y - P.y) * Nn.y + (z - P.z) * Nn.z;
                float ip = fmaxf(THRESH - d, 0.0f);
                float f = ip * ip * ip;
                fsum += f;
                if (tf < lmin) { lmin = tf; fmin = f; }
                if (tf < s7) {
                    s7 = tf;
                    CSW(s6, s7); CSW(s5, s6); CSW(s4, s5); CSW(s3, s4);
                    CSW(s2, s3); CSW(s1, s2); CSW(s0, s1);
                }
            }
        }
    }

    // fused 5-step butterfly within the half-wave:
    // (sum cnt, sum f, argmin pair) simultaneously
    int   c_ = cnt;
    float fs = fsum;
    int   lm = lmin;
    float fm = fmin;
    #pragma unroll
    for (int m = 16; m; m >>= 1) {
        int   oc = __shfl_xor(c_, m);
        float os = __shfl_xor(fs, m);
        int   ol = __shfl_xor(lm, m);
        float of = __shfl_xor(fm, m);
        c_ += oc;
        fs += os;
        if (ol < lm) { lm = ol; fm = of; }
    }
    int cnt_tot = c_;            // uniform within half-wave

    float lsum;
    if (cnt_tot == 0) {
        float d0 = (x - P0.x) * N0.x + (y - P0.y) * N0.y + (z - P0.z) * N0.z;
        float ip0 = fmaxf(THRESH - d0, 0.0f);
        lsum = 8.0f * (ip0 * ip0 * ip0);
    } else if (cnt_tot <= 8) {
        // selected set == all hits; pad (8-cnt) copies of the min-id hit
        lsum = fs + (float)(8 - cnt_tot) * fm;
    } else {
        // slow path: extract the 8 smallest ids (unique across lanes)
        int t0, t1, t2, t3, t4, t5, t6, t7;
#define EXTRACT(TK)                                                      \
        {                                                                \
            int m = half_min_i(s0);                                      \
            TK = m;                                                      \
            bool p = (s0 == m);                                          \
            s0 = p ? s1 : s0; s1 = p ? s2 : s1; s2 = p ? s3 : s2;        \
            s3 = p ? s4 : s3; s4 = p ? s5 : s4; s5 = p ? s6 : s5;        \
            s6 = p ? s7 : s6; s7 = p ? INT_MAX : s7;                     \
        }
        EXTRACT(t0) EXTRACT(t1) EXTRACT(t2) EXTRACT(t3)
        EXTRACT(t4) EXTRACT(t5) EXTRACT(t6) EXTRACT(t7)
#undef EXTRACT
        int v = t0;
        v = (l32 == 1) ? t1 : v;
        v = (l32 == 2) ? t2 : v;
        v = (l32 == 3) ? t3 : v;
        v = (l32 == 4) ? t4 : v;
        v = (l32 == 5) ? t5 : v;
        v = (l32 == 6) ? t6 : v;
        v = (l32 == 7) ? t7 : v;
        float4 P  = posn[2 * v];
        float4 Nn = posn[2 * v + 1];
        float d = (x - P.x) * Nn.x + (y - P.y) * Nn.y + (z - P.z) * Nn.z;
        float ip = fmaxf(THRESH - d, 0.0f);
        float c = ip * ip * ip;
        c = (l32 < 8) ? c : 0.0f;
        #pragma unroll
        for (int m = 16; m; m >>= 1) c += __shfl_xor(c, m);
        lsum = c;
    }

    if (l32 == 0) ws[hw] = lsum;
    __syncthreads();
    if (tid == 0) {
        float s = 0.0f;
        #pragma unroll
        for (int k = 0; k < QPB; ++k) s += ws[k];
        partials[blockIdx.x] = s;   // plain store; kernel boundary orders it
    }
}

// ---------------- Kernel 3: final reduce -----------------------------------
__global__ __launch_bounds__(1024) void reduce_kernel(
    const float* __restrict__ partials, float* __restrict__ out)
{
    float s = 0.0f;
    for (int i = threadIdx.x; i < QBLOCKS; i += 1024)
        s += partials[i];
    s = wave_add_f(s);
    __shared__ float ws[16];
    int lane = threadIdx.x & 63, w = threadIdx.x >> 6;
    if (lane == 0) ws[w] = s;
    __syncthreads();
    if (threadIdx.x == 0) {
        float t = 0.0f;
        #pragma unroll
        for (int i = 0; i < 16; ++i) t += ws[i];
        out[0] = t * SCALE;   // single plain store to d_out
    }
}

extern "C" void kernel_launch(void* const* d_in, const int* in_sizes, int n_in,
                              void* d_out, int out_size, void* d_ws, size_t ws_size,
                              hipStream_t stream) {
    const float* pred    = (const float*)d_in[0];
    const float* state   = (const float*)d_in[1];
    const float* h_state = (const float*)d_in[2];
    const int*   h_faces = (const int*)d_in[3];
    float* out = (float*)d_out;

    // workspace layout (~8.0 MB)
    float4* posn    = (float4*)d_ws;                     // 2*NBF
    float4* buckets = posn + 2 * NBF;                    // T_CELLS*CAP
    int* cellCnt    = (int*)(buckets + (size_t)T_CELLS * CAP); // T_CELLS
    float* partials = (float*)(cellCnt + T_CELLS);       // QBLOCKS

    hipMemsetAsync(cellCnt, 0, (size_t)T_CELLS * sizeof(int), stream);

    face_kernel<<<dim3((NBF + 255) / 256), 256, 0, stream>>>(
        h_state, h_faces, posn, buckets, cellCnt);

    query_kernel<<<dim3(QBLOCKS), 256, 0, stream>>>(
        state, pred, buckets, posn, cellCnt, partials);

    reduce_kernel<<<dim3(1), 1024, 0, stream>>>(partials, out);
}